// Round 1
// baseline (420.533 us; speedup 1.0000x reference)
//
#include <hip/hip_runtime.h>
#include <hip/hip_bf16.h>
#include <math.h>

// Problem constants (fixed by setup_inputs):
// B=16, T=8, NT=128, C=512, H=W=28, HW=784, c8=64
constexpr int NT  = 128;
constexpr int C   = 512;
constexpr int HW  = 784;      // 28*28, = 196 float4
constexpr int C8  = 64;
constexpr int TT  = 8;
constexpr int BB  = 16;
constexpr float EPS = 1e-5f;

// K1: spatial mean. One wave (64 lanes) per (nt,c) row of 784 floats.
// Block = 256 threads = 4 waves = 4 rows; grid = 65536/4 = 16384.
__global__ void k_mean(const float* __restrict__ x, float* __restrict__ xv) {
    const int wave = threadIdx.x >> 6;
    const int lane = threadIdx.x & 63;
    const size_t row = (size_t)blockIdx.x * 4 + wave;   // 0..65535
    const float4* p = (const float4*)(x + row * HW);
    float s = 0.f;
    #pragma unroll
    for (int j = lane; j < HW / 4; j += 64) {           // 196 float4 per row
        float4 v = p[j];
        s += v.x + v.y + v.z + v.w;
    }
    #pragma unroll
    for (int off = 32; off; off >>= 1) s += __shfl_xor(s, off);
    if (lane == 0) xv[row] = s * (1.0f / HW);
}

// K2: left/right = relu(bn(xv @ w^T)). One block per bt (128 blocks), 256 threads.
// 128 outputs per block (64 left + 64 right), 2 threads per output (256-MAC halves).
__global__ void k_lr(const float* __restrict__ xv,
                     const float* __restrict__ w1,
                     const float* __restrict__ g1, const float* __restrict__ b1,
                     const float* __restrict__ m1, const float* __restrict__ v1,
                     const float* __restrict__ w2,
                     const float* __restrict__ g2, const float* __restrict__ b2,
                     const float* __restrict__ m2, const float* __restrict__ v2,
                     float* __restrict__ lr) {
    __shared__ float sx[C];
    const int bt = blockIdx.x;
    for (int i = threadIdx.x; i < C; i += 256) sx[i] = xv[bt * C + i];
    __syncthreads();

    const int out  = threadIdx.x >> 1;   // 0..127
    const int half = threadIdx.x & 1;
    const int j    = out & 63;
    const float* w = (out < C8) ? (w1 + (size_t)j * C) : (w2 + (size_t)j * C);
    const int k0 = half * (C / 2);
    float acc = 0.f;
    #pragma unroll 8
    for (int k = 0; k < C / 2; ++k) acc = fmaf(sx[k0 + k], w[k0 + k], acc);
    acc += __shfl_xor(acc, 1);
    if (half == 0) {
        float y;
        if (out < C8) y = (acc - m1[j]) * rsqrtf(v1[j] + EPS) * g1[j] + b1[j];
        else          y = (acc - m2[j]) * rsqrtf(v2[j] + EPS) * g2[j] + b2[j];
        lr[bt * 2 * C8 + out] = fmaxf(y, 0.f);
    }
}

// K3: the temporal scan. One wave per batch (16 blocks x 64 threads).
// diff[b,t] = left[b,t] - right[b,t+1] (t<T-1), else 1.  state0 = ones.
// z = dot(d_t, gw[:64]) + dot(state, gw[64:]) + gb ; g = sigmoid(z) (scalar!)
// state = g*d_t + (1-g)*state ; New[b,t,:] = state
__global__ void k_scan(const float* __restrict__ lr,
                       const float* __restrict__ gamma_w,
                       const float* __restrict__ gamma_b,
                       float* __restrict__ Nw) {
    const int b = blockIdx.x;    // 0..15
    const int j = threadIdx.x;   // 0..63
    const float gw0 = gamma_w[j];
    const float gw1 = gamma_w[C8 + j];
    const float gb  = gamma_b[0];

    float d[TT];
    #pragma unroll
    for (int t = 0; t < TT - 1; ++t)
        d[t] = lr[(b * TT + t) * (2 * C8) + j]
             - lr[(b * TT + t + 1) * (2 * C8) + C8 + j];
    d[TT - 1] = 1.0f;

    float state = 1.0f;
    #pragma unroll
    for (int t = 0; t < TT; ++t) {
        float part = d[t] * gw0 + state * gw1;
        #pragma unroll
        for (int off = 32; off; off >>= 1) part += __shfl_xor(part, off);
        const float g = 1.f / (1.f + expf(-(part + gb)));
        state = d[t] * g + state * (1.f - g);
        Nw[(b * TT + t) * C8 + j] = state;
    }
}

// K4: sig[bt,c] = sigmoid(dot(New[bt], Wa_w[c]) + Wa_b[c]). 128 blocks x 256 thr.
__global__ void k_att(const float* __restrict__ Nw,
                      const float* __restrict__ Wa_w,
                      const float* __restrict__ Wa_b,
                      float* __restrict__ sig) {
    __shared__ float sn[C8];
    const int bt = blockIdx.x;
    if (threadIdx.x < C8) sn[threadIdx.x] = Nw[bt * C8 + threadIdx.x];
    __syncthreads();
    for (int c = threadIdx.x; c < C; c += 256) {
        const float* w = Wa_w + (size_t)c * C8;
        float acc = Wa_b[c];
        #pragma unroll 16
        for (int k = 0; k < C8; ++k) acc = fmaf(sn[k], w[k], acc);
        sig[bt * C + c] = 1.f / (1.f + expf(-acc));
    }
}

// K5: out[row, :] = x[row, :] * sig[row], row = bt*C + c. Wave per row, float4.
__global__ void k_scale(const float* __restrict__ x,
                        const float* __restrict__ sig,
                        float* __restrict__ out) {
    const int wave = threadIdx.x >> 6;
    const int lane = threadIdx.x & 63;
    const size_t row = (size_t)blockIdx.x * 4 + wave;
    const float s = sig[row];
    const float4* px = (const float4*)(x + row * HW);
    float4*       po = (float4*)(out + row * HW);
    #pragma unroll
    for (int j = lane; j < HW / 4; j += 64) {
        float4 v = px[j];
        v.x *= s; v.y *= s; v.z *= s; v.w *= s;
        po[j] = v;
    }
}

extern "C" void kernel_launch(void* const* d_in, const int* in_sizes, int n_in,
                              void* d_out, int out_size, void* d_ws, size_t ws_size,
                              hipStream_t stream) {
    const float* x     = (const float*)d_in[0];
    const float* w1    = (const float*)d_in[1];
    const float* bn1_g = (const float*)d_in[2];
    const float* bn1_b = (const float*)d_in[3];
    const float* bn1_m = (const float*)d_in[4];
    const float* bn1_v = (const float*)d_in[5];
    const float* w2    = (const float*)d_in[6];
    const float* bn2_g = (const float*)d_in[7];
    const float* bn2_b = (const float*)d_in[8];
    const float* bn2_m = (const float*)d_in[9];
    const float* bn2_v = (const float*)d_in[10];
    const float* Wa_w  = (const float*)d_in[11];
    const float* Wa_b  = (const float*)d_in[12];
    const float* gamma_w = (const float*)d_in[13];
    const float* gamma_b = (const float*)d_in[14];
    float* out = (float*)d_out;

    // workspace layout (floats): xv[65536] | lr[16384] | New[8192] | sig[65536]
    float* ws  = (float*)d_ws;
    float* xv  = ws;
    float* lr  = xv + NT * C;
    float* Nw  = lr + NT * 2 * C8;
    float* sig = Nw + NT * C8;

    const int rows = NT * C;                 // 65536
    k_mean <<<rows / 4, 256, 0, stream>>>(x, xv);
    k_lr   <<<NT, 256, 0, stream>>>(xv, w1, bn1_g, bn1_b, bn1_m, bn1_v,
                                        w2, bn2_g, bn2_b, bn2_m, bn2_v, lr);
    k_scan <<<BB, 64, 0, stream>>>(lr, gamma_w, gamma_b, Nw);
    k_att  <<<NT, 256, 0, stream>>>(Nw, Wa_w, Wa_b, sig);
    k_scale<<<rows / 4, 256, 0, stream>>>(x, sig, out);
}